// Round 8
// baseline (279.784 us; speedup 1.0000x reference)
//
#include <hip/hip_runtime.h>
#include <math.h>

#ifndef M_PI
#define M_PI 3.14159265358979323846
#endif

#define NAANG 1152
#define NDET  736
#define NPIX  512
#define PADN  2048
#define NHALF 1025   // PADN/2 + 1

// ---- workspace layout (byte offsets) ----
// float  filt_f[1025]          @ 0        (4100 B, pad 4224)
// float  h[2048]               @ 4224     (8192 B)  [pi/(2NA) scale folded]
// float4 trig[1152]            @ 12416    (18432 B) (cb, sb, K*cb, K*sb)
// float  filtered[1152*736]    @ 30848    (3391488 B)
// float  partial[NCH*512*512]  @ 3422336  (NCH MiB)
#define OFF_FILTF 0
#define OFF_H     4224
#define OFF_TRIG  12416
#define OFF_FS    30848
#define OFF_PART  3422336

typedef float f32x2 __attribute__((ext_vector_type(2)));

// ---------------------------------------------------------------------------
// Kernel 1: FILT[m], Shepp-Logan half-spectrum.
// cos(2*pi*r/2048) = cospif(r/1024) with r=(m*(2j+1))&2047 -> args <= 2,
// fp32 fast path (the R1-R6 double-cos with args up to ~6400 was the hidden
// Payne-Hanek cost theory — disproven; cospif kept anyway, it's simplest).
// ---------------------------------------------------------------------------
__global__ void filt_spec_kernel(float* __restrict__ filt_f) {
    __shared__ float red[256];
    const int m = blockIdx.x;          // 0..1024
    const int t = threadIdx.x;
    float s = 0.f;
    for (int j = t; j < 1024; j += 256) {
        int n = (j < 512) ? (2 * j + 1) : (2047 - 2 * j);
        float fj = (float)(-1.0 / ((M_PI * n) * (M_PI * n)));
        int r = (m * (2 * j + 1)) & (PADN - 1);
        s += fj * cospif((float)r * (1.0f / 1024.0f));
    }
    red[t] = s;
    __syncthreads();
    for (int w = 128; w > 0; w >>= 1) {
        if (t < w) red[t] += red[t + w];
        __syncthreads();
    }
    if (t == 0) {
        double four = 2.0 * (0.25 + (double)red[0]);
        if (m > 0) {
            double om = M_PI * (double)m / (double)PADN;
            four *= sin(om) / om;      // small arg, fast path
        }
        filt_f[m] = (float)four;
    }
}

// ---------------------------------------------------------------------------
// Kernel 2: h[k] = irfft(FILT,2048)[k] * pi/(2*NA); blocks k<1152 also fill
// the trig table on lane 0 (small-arg double trig).
// ---------------------------------------------------------------------------
__global__ void h_kernel(const float* __restrict__ filt_f,
                         float* __restrict__ h, float4* __restrict__ trig) {
    __shared__ float red[256];
    const int k = blockIdx.x;          // 0..2047
    const int t = threadIdx.x;
    if (t == 0 && k < NAANG) {
        double ang = 2.0 * M_PI * (double)k / (double)NAANG + M_PI / 2.0;
        double c = cos(ang), s = sin(ang);
        double K = 1085.6 / 1.2858;    // DSD/DU (vox scaling cancels)
        trig[k] = make_float4((float)c, (float)s, (float)(K * c), (float)(K * s));
    }
    float s = 0.f;
    for (int m = t; m <= 1024; m += 256) {
        float F = filt_f[m];
        float c;
        if (m == 0) c = 1.f;
        else if (m == 1024) c = (k & 1) ? -1.f : 1.f;
        else c = 2.f * cospif((float)((m * k) & (PADN - 1)) * (1.0f / 1024.0f));
        s += F * c;
    }
    red[t] = s;
    __syncthreads();
    for (int w = 128; w > 0; w >>= 1) {
        if (t < w) red[t] += red[t + w];
        __syncthreads();
    }
    if (t == 0)
        h[k] = (float)((double)red[0] / (double)PADN * (M_PI / (2.0 * (double)NAANG)));
}

// ---------------------------------------------------------------------------
// Kernel 3: circular convolution, 8-output x 8-tap register tile.
// Block = 192 threads, 2 rows (r = t/96, u = t%96, u<92 active).
// Per 8-tap group: 4 aligned b128 h-window (per-lane) + 2 b128 broadcast
// (srow) for 64 FMAs -> VALU-bound (~2.2 cyc/MAC) instead of LDS-bound.
// ---------------------------------------------------------------------------
__global__ void conv_kernel(const float* __restrict__ x,
                            const float* __restrict__ h,
                            float* __restrict__ fs) {
    __shared__ float sh2[2816];        // h duplicated: sh2[i] = h[i & 2047]
    __shared__ float srow[2][NDET];    // contiguous pair of rows
    const int t = threadIdx.x;         // 0..191
    const int row0 = blockIdx.x * 2;
    const float4* h4 = (const float4*)h;
    for (int i = t; i < 704; i += 192) ((float4*)sh2)[i] = h4[i & 511];
    const float4* x4 = (const float4*)(x + (size_t)row0 * NDET);
    for (int i = t; i < 368; i += 192) ((float4*)srow[0])[i] = x4[i];
    __syncthreads();

    const int r = t / 96;
    const int u = t % 96;
    const float* my = srow[r];
    const int A0 = 8 * u + PADN;       // h index base: A = A0 - j
    float o[8] = {0.f, 0.f, 0.f, 0.f, 0.f, 0.f, 0.f, 0.f};
    #pragma unroll 2
    for (int j = 0; j < NDET; j += 8) {
        float4 s0 = *(const float4*)&my[j];
        float4 s1 = *(const float4*)&my[j + 4];
        const float* hp = &sh2[A0 - j - 8];     // aligned: index mult of 4
        float4 h0 = *(const float4*)(hp);
        float4 h1 = *(const float4*)(hp + 4);
        float4 h2 = *(const float4*)(hp + 8);
        float4 h3 = *(const float4*)(hp + 12);
        float wv[16] = {h0.x, h0.y, h0.z, h0.w, h1.x, h1.y, h1.z, h1.w,
                        h2.x, h2.y, h2.z, h2.w, h3.x, h3.y, h3.z, h3.w};
        float se[8]  = {s0.x, s0.y, s0.z, s0.w, s1.x, s1.y, s1.z, s1.w};
        #pragma unroll
        for (int e = 0; e < 8; ++e) {
            #pragma unroll
            for (int d = 0; d < 8; ++d)
                o[d] = fmaf(se[e], wv[8 + d - e], o[d]);   // h[(8u+d)-(j+e)]
        }
    }
    if (u < 92) {
        float* op = fs + (size_t)(row0 + r) * NDET + 8 * u;
        *(float4*)op       = make_float4(o[0], o[1], o[2], o[3]);
        *(float4*)(op + 4) = make_float4(o[4], o[5], o[6], o[7]);
    }
}

// ---------------------------------------------------------------------------
// Kernel 4: fan-beam backprojection — LDS gathers with GROUPED staging.
// Groups of 2 angles (2 contiguous rows = 368 float4s) double-buffered in
// LDS. Per group: issue next group's coalesced float4 prefetch into regs,
// compute 2 angles (4 px/thread) gathering from LDS (removes the ~80-100 µs
// L1/TD scattered-gather floor), ds_write prefetch into the other buffer,
// ONE barrier. 72 barriers total (vs R5's 144 every-angle convoy).
// grid (2, 128, NCH); NCH=8 -> 2048 blocks = 8/CU * 4 waves = 32 waves/CU.
// LDS = 2.3 KB trig + 11.5 KB rows ~= 14 KB -> 8 blocks/CU fits (113 KB).
// ---------------------------------------------------------------------------
template<int NCH>
__global__ __launch_bounds__(256, 8)
void backproj_kernel(const float* __restrict__ fs,
                     const float4* __restrict__ trig,
                     float* __restrict__ partial) {
    constexpr int ACL = NAANG / NCH;
    constexpr int NG  = ACL / 2;       // groups of 2 angles
    __shared__ float4 st[ACL];
    __shared__ float rows[2][2 * NDET];
    const int t = threadIdx.x;
    const int abase = blockIdx.z * ACL;
    for (int i = t; i < ACL; i += 256) st[i] = trig[abase + i];
    {
        const float4* src = (const float4*)(fs + (size_t)abase * NDET);
        float4* dst = (float4*)rows[0];
        dst[t] = src[t];
        if (t < 112) dst[t + 256] = src[t + 256];   // 368 float4s = 2 rows
    }
    __syncthreads();

    const int ix = blockIdx.x * 256 + t;
    const int iy = blockIdx.y * 4;
    const float xs  = (float)ix - 255.5f;
    const float ys0 = (float)iy - 255.5f;
    const float Dg = 850.0f;           // 595/0.7 exactly

    float acc0 = 0.f, acc1 = 0.f, acc2 = 0.f, acc3 = 0.f;
    for (int g = 0; g < NG; ++g) {
        float4 p0, p1;
        const bool pf = (g + 1 < NG);
        if (pf) {
            const float4* src =
                (const float4*)(fs + (size_t)(abase + 2 * (g + 1)) * NDET);
            p0 = src[t];
            if (t < 112) p1 = src[t + 256];
        }
        const float* bufb = rows[g & 1];
        #pragma unroll
        for (int gg = 0; gg < 2; ++gg) {
            const float* row = bufb + gg * NDET;
            float4 q = st[2 * g + gg];            // cb, sb, K*cb, K*sb
            float sb2 = q.y + q.y, kc2 = q.z + q.z;
            float den0 = fmaf(-xs, q.x, fmaf(-ys0, q.y, Dg));
            float kpe0 = fmaf(ys0, q.z, -(xs * q.w));
            float den1 = den0 - q.y, den2 = den0 - sb2, den3 = den2 - q.y;
            float kpe1 = kpe0 + q.z, kpe2 = kpe0 + kc2, kpe3 = kpe2 + q.z;
            float r0 = __builtin_amdgcn_rcpf(den0);
            float r1 = __builtin_amdgcn_rcpf(den1);
            float r2 = __builtin_amdgcn_rcpf(den2);
            float r3 = __builtin_amdgcn_rcpf(den3);
            float iu0 = fmaf(kpe0, r0, 367.5f);   // (ND-1)/2
            float iu1 = fmaf(kpe1, r1, 367.5f);
            float iu2 = fmaf(kpe2, r2, 367.5f);
            float iu3 = fmaf(kpe3, r3, 367.5f);
            float f0 = floorf(iu0), f1 = floorf(iu1);
            float f2 = floorf(iu2), f3 = floorf(iu3);
            int i0 = (int)f0, i1 = (int)f1, i2 = (int)f2, i3 = (int)f3;
            int c0 = min(max(i0, 0), NDET - 2);
            int c1 = min(max(i1, 0), NDET - 2);
            int c2 = min(max(i2, 0), NDET - 2);
            int c3 = min(max(i3, 0), NDET - 2);
            float a0 = row[c0], b0 = row[c0 + 1];
            float a1 = row[c1], b1 = row[c1 + 1];
            float a2 = row[c2], b2 = row[c2 + 1];
            float a3 = row[c3], b3 = row[c3 + 1];
            float fr0 = iu0 - f0, fr1 = iu1 - f1;
            float fr2 = iu2 - f2, fr3 = iu3 - f3;
            float v0 = fmaf(fr0, b0 - a0, a0);
            float v1 = fmaf(fr1, b1 - a1, a1);
            float v2 = fmaf(fr2, b2 - a2, a2);
            float v3 = fmaf(fr3, b3 - a3, a3);
            float d0 = Dg * r0, d1 = Dg * r1, d2 = Dg * r2, d3 = Dg * r3;
            float w0 = ((unsigned)i0 < (unsigned)(NDET - 1)) ? d0 * d0 : 0.f;
            float w1 = ((unsigned)i1 < (unsigned)(NDET - 1)) ? d1 * d1 : 0.f;
            float w2 = ((unsigned)i2 < (unsigned)(NDET - 1)) ? d2 * d2 : 0.f;
            float w3 = ((unsigned)i3 < (unsigned)(NDET - 1)) ? d3 * d3 : 0.f;
            acc0 = fmaf(w0, v0, acc0);
            acc1 = fmaf(w1, v1, acc1);
            acc2 = fmaf(w2, v2, acc2);
            acc3 = fmaf(w3, v3, acc3);
        }
        if (pf) {
            float4* dst = (float4*)rows[(g + 1) & 1];
            dst[t] = p0;
            if (t < 112) dst[t + 256] = p1;
        }
        __syncthreads();
    }
    float* outp = partial + ((size_t)blockIdx.z * NPIX + iy) * NPIX + ix;
    outp[0 * NPIX] = acc0;
    outp[1 * NPIX] = acc1;
    outp[2 * NPIX] = acc2;
    outp[3 * NPIX] = acc3;
}

// ---------------------------------------------------------------------------
// Kernel 5: sum partials + HU window.
// ---------------------------------------------------------------------------
template<int NCH>
__global__ void combine_kernel(const float* __restrict__ partial,
                               float* __restrict__ out) {
    int p = blockIdx.x * 256 + threadIdx.x;
    float s = 0.f;
    #pragma unroll
    for (int c = 0; c < NCH; ++c) s += partial[c * NPIX * NPIX + p];
    // (1000*((fbp-0.0192)/0.0192)+1024)/4096 = fbp*(1000/0.0192/4096) + 24/4096
    out[p] = fmaf(s, (float)(1000.0 / 0.0192 / 4096.0), 0.005859375f);
}

extern "C" void kernel_launch(void* const* d_in, const int* in_sizes, int n_in,
                              void* d_out, int out_size, void* d_ws, size_t ws_size,
                              hipStream_t stream) {
    const float* x = (const float*)d_in[0];     // (1,1,1152,736) fp32 sinogram
    float* out = (float*)d_out;                 // (1,1,512,512) fp32

    char* ws = (char*)d_ws;
    float*  filt_f = (float*)(ws + OFF_FILTF);
    float*  h      = (float*)(ws + OFF_H);
    float4* trig   = (float4*)(ws + OFF_TRIG);
    float*  fs     = (float*)(ws + OFF_FS);
    float*  part   = (float*)(ws + OFF_PART);

    filt_spec_kernel<<<NHALF, 256, 0, stream>>>(filt_f);
    h_kernel<<<PADN, 256, 0, stream>>>(filt_f, h, trig);
    conv_kernel<<<NAANG / 2, 192, 0, stream>>>(x, h, fs);

    const size_t pbytes = (size_t)NPIX * NPIX * 4;
    if (ws_size >= OFF_PART + 8 * pbytes) {
        backproj_kernel<8><<<dim3(2, 128, 8), 256, 0, stream>>>(fs, trig, part);
        combine_kernel<8><<<NPIX * NPIX / 256, 256, 0, stream>>>(part, out);
    } else if (ws_size >= OFF_PART + 4 * pbytes) {
        backproj_kernel<4><<<dim3(2, 128, 4), 256, 0, stream>>>(fs, trig, part);
        combine_kernel<4><<<NPIX * NPIX / 256, 256, 0, stream>>>(part, out);
    } else if (ws_size >= OFF_PART + 2 * pbytes) {
        backproj_kernel<2><<<dim3(2, 128, 2), 256, 0, stream>>>(fs, trig, part);
        combine_kernel<2><<<NPIX * NPIX / 256, 256, 0, stream>>>(part, out);
    } else {
        backproj_kernel<1><<<dim3(2, 128, 1), 256, 0, stream>>>(fs, trig, part);
        combine_kernel<1><<<NPIX * NPIX / 256, 256, 0, stream>>>(part, out);
    }
}

// Round 10
// 269.353 us; speedup vs baseline: 1.0387x; 1.0387x over previous
//
#include <hip/hip_runtime.h>
#include <math.h>

#ifndef M_PI
#define M_PI 3.14159265358979323846
#endif

#define NAANG 1152
#define NDET  736
#define NPIX  512
#define PADN  2048
#define NHALF 1025   // PADN/2 + 1

// ---- workspace layout (byte offsets) ----
// float  filt_f[1025]          @ 0        (pad to 4224)
// float  h[2048]               @ 4224     (8192 B)  [pi/(2NA) scale folded]
// float4 trig[1152]            @ 12416    (18432 B) (cb, sb, K*cb, K*sb)
// float  filtered[1152*736]    @ 30848    (3391488 B)
// float  partial[NCH*512*512]  @ 3422336  (NCH MiB)
#define OFF_FILTF 0
#define OFF_H     4224
#define OFF_TRIG  12416
#define OFF_FS    30848
#define OFF_PART  3422336

typedef float f32x2 __attribute__((ext_vector_type(2)));

static __device__ __forceinline__ f32x2 load2(const float* p) {
    f32x2 r;
    __builtin_memcpy(&r, p, 8);
    return r;
}

// ---------------------------------------------------------------------------
// Kernel 1: FILT[m], Shepp-Logan half-spectrum (cospif args <= 2, fast path).
// ---------------------------------------------------------------------------
__global__ void filt_spec_kernel(float* __restrict__ filt_f) {
    __shared__ float red[256];
    const int m = blockIdx.x;          // 0..1024
    const int t = threadIdx.x;
    float s = 0.f;
    for (int j = t; j < 1024; j += 256) {
        int n = (j < 512) ? (2 * j + 1) : (2047 - 2 * j);
        float fj = (float)(-1.0 / ((M_PI * n) * (M_PI * n)));
        int r = (m * (2 * j + 1)) & (PADN - 1);
        s += fj * cospif((float)r * (1.0f / 1024.0f));
    }
    red[t] = s;
    __syncthreads();
    for (int w = 128; w > 0; w >>= 1) {
        if (t < w) red[t] += red[t + w];
        __syncthreads();
    }
    if (t == 0) {
        double four = 2.0 * (0.25 + (double)red[0]);
        if (m > 0) {
            double om = M_PI * (double)m / (double)PADN;
            four *= sin(om) / om;
        }
        filt_f[m] = (float)four;
    }
}

// ---------------------------------------------------------------------------
// Kernel 2: h[k] = irfft(FILT,2048)[k] * pi/(2*NA); blocks k<1152 also fill
// the trig table on lane 0 (small-arg double trig).
// ---------------------------------------------------------------------------
__global__ void h_kernel(const float* __restrict__ filt_f,
                         float* __restrict__ h, float4* __restrict__ trig) {
    __shared__ float red[256];
    const int k = blockIdx.x;          // 0..2047
    const int t = threadIdx.x;
    if (t == 0 && k < NAANG) {
        double ang = 2.0 * M_PI * (double)k / (double)NAANG + M_PI / 2.0;
        double c = cos(ang), s = sin(ang);
        double K = 1085.6 / 1.2858;    // DSD/DU (vox scaling cancels)
        trig[k] = make_float4((float)c, (float)s, (float)(K * c), (float)(K * s));
    }
    float s = 0.f;
    for (int m = t; m <= 1024; m += 256) {
        float F = filt_f[m];
        float c;
        if (m == 0) c = 1.f;
        else if (m == 1024) c = (k & 1) ? -1.f : 1.f;
        else c = 2.f * cospif((float)((m * k) & (PADN - 1)) * (1.0f / 1024.0f));
        s += F * c;
    }
    red[t] = s;
    __syncthreads();
    for (int w = 128; w > 0; w >>= 1) {
        if (t < w) red[t] += red[t + w];
        __syncthreads();
    }
    if (t == 0)
        h[k] = (float)((double)red[0] / (double)PADN * (M_PI / (2.0 * (double)NAANG)));
}

// ---------------------------------------------------------------------------
// Kernel 3: circular convolution, 8-output x 8-tap register tile
// (unchanged from R8, which passed with absmax 3.9e-3).
// ---------------------------------------------------------------------------
__global__ void conv_kernel(const float* __restrict__ x,
                            const float* __restrict__ h,
                            float* __restrict__ fs) {
    __shared__ float sh2[2816];        // h duplicated: sh2[i] = h[i & 2047]
    __shared__ float srow[2][NDET];
    const int t = threadIdx.x;         // 0..191
    const int row0 = blockIdx.x * 2;
    const float4* h4 = (const float4*)h;
    for (int i = t; i < 704; i += 192) ((float4*)sh2)[i] = h4[i & 511];
    const float4* x4 = (const float4*)(x + (size_t)row0 * NDET);
    for (int i = t; i < 368; i += 192) ((float4*)srow[0])[i] = x4[i];
    __syncthreads();

    const int r = t / 96;
    const int u = t % 96;
    const float* my = srow[r];
    const int A0 = 8 * u + PADN;
    float o[8] = {0.f, 0.f, 0.f, 0.f, 0.f, 0.f, 0.f, 0.f};
    #pragma unroll 2
    for (int j = 0; j < NDET; j += 8) {
        float4 s0 = *(const float4*)&my[j];
        float4 s1 = *(const float4*)&my[j + 4];
        const float* hp = &sh2[A0 - j - 8];
        float4 h0 = *(const float4*)(hp);
        float4 h1 = *(const float4*)(hp + 4);
        float4 h2 = *(const float4*)(hp + 8);
        float4 h3 = *(const float4*)(hp + 12);
        float wv[16] = {h0.x, h0.y, h0.z, h0.w, h1.x, h1.y, h1.z, h1.w,
                        h2.x, h2.y, h2.z, h2.w, h3.x, h3.y, h3.z, h3.w};
        float se[8]  = {s0.x, s0.y, s0.z, s0.w, s1.x, s1.y, s1.z, s1.w};
        #pragma unroll
        for (int e = 0; e < 8; ++e) {
            #pragma unroll
            for (int d = 0; d < 8; ++d)
                o[d] = fmaf(se[e], wv[8 + d - e], o[d]);
        }
    }
    if (u < 92) {
        float* op = fs + (size_t)(row0 + r) * NDET + 8 * u;
        *(float4*)op       = make_float4(o[0], o[1], o[2], o[3]);
        *(float4*)(op + 4) = make_float4(o[4], o[5], o[6], o[7]);
    }
}

// ---------------------------------------------------------------------------
// Kernel 4: fan-beam backprojection — 2D wave tiles + L1 gathers + pipeline.
// Wave = 16x16 pixel tile (lane: lx=lane&15, lq=lane>>4; 4 consecutive y per
// thread) -> gather u-span per wave ~2.5x smaller than 64x1 mapping -> fewer
// L1/TD line transactions (the R7 bottleneck theory, testing cleanly now).
// EXACT reference validity restored (R9's zero-pad ramp broke the hard
// detector window): w = r^2 iff i0 in [0, NDET-2], else 0; Dg^2 in combine.
// grid (16,16,NCH); NCH=8 -> 2048 blocks = 8/CU = 32 waves/CU.
// ---------------------------------------------------------------------------
#define GEO(AA, QQ, G0,G1,G2,G3, FR0,FR1,FR2,FR3, W0,W1,W2,W3)           \
  {                                                                      \
    const float* rp = fs + (size_t)(abase + (AA)) * NDET;                \
    float den0 = fmaf(-xs, QQ.x, fmaf(-ys0, QQ.y, Dg));                  \
    float kpe0 = fmaf(ys0, QQ.z, -(xs * QQ.w));                          \
    float sb2 = QQ.y + QQ.y, kc2 = QQ.z + QQ.z;                          \
    float den1 = den0 - QQ.y, den2 = den0 - sb2, den3 = den2 - QQ.y;     \
    float kpe1 = kpe0 + QQ.z, kpe2 = kpe0 + kc2, kpe3 = kpe2 + QQ.z;     \
    float r0 = __builtin_amdgcn_rcpf(den0);                              \
    float r1 = __builtin_amdgcn_rcpf(den1);                              \
    float r2 = __builtin_amdgcn_rcpf(den2);                              \
    float r3 = __builtin_amdgcn_rcpf(den3);                              \
    float iu0 = fmaf(kpe0, r0, 367.5f);                                  \
    float iu1 = fmaf(kpe1, r1, 367.5f);                                  \
    float iu2 = fmaf(kpe2, r2, 367.5f);                                  \
    float iu3 = fmaf(kpe3, r3, 367.5f);                                  \
    float f0 = floorf(iu0), f1 = floorf(iu1);                            \
    float f2 = floorf(iu2), f3 = floorf(iu3);                            \
    int i0 = (int)f0, i1 = (int)f1, i2 = (int)f2, i3 = (int)f3;          \
    int c0 = min(max(i0, 0), NDET - 2);                                  \
    int c1 = min(max(i1, 0), NDET - 2);                                  \
    int c2 = min(max(i2, 0), NDET - 2);                                  \
    int c3 = min(max(i3, 0), NDET - 2);                                  \
    G0 = load2(rp + c0); G1 = load2(rp + c1);                            \
    G2 = load2(rp + c2); G3 = load2(rp + c3);                            \
    FR0 = iu0 - f0; FR1 = iu1 - f1; FR2 = iu2 - f2; FR3 = iu3 - f3;      \
    W0 = ((unsigned)i0 < (unsigned)(NDET - 1)) ? r0 * r0 : 0.f;          \
    W1 = ((unsigned)i1 < (unsigned)(NDET - 1)) ? r1 * r1 : 0.f;          \
    W2 = ((unsigned)i2 < (unsigned)(NDET - 1)) ? r2 * r2 : 0.f;          \
    W3 = ((unsigned)i3 < (unsigned)(NDET - 1)) ? r3 * r3 : 0.f;          \
  }

#define CONSUME(G0,G1,G2,G3, FR0,FR1,FR2,FR3, W0,W1,W2,W3)               \
  {                                                                      \
    float v0 = fmaf(FR0, G0.y - G0.x, G0.x);                             \
    float v1 = fmaf(FR1, G1.y - G1.x, G1.x);                             \
    float v2 = fmaf(FR2, G2.y - G2.x, G2.x);                             \
    float v3 = fmaf(FR3, G3.y - G3.x, G3.x);                             \
    acc0 = fmaf(W0, v0, acc0); acc1 = fmaf(W1, v1, acc1);                \
    acc2 = fmaf(W2, v2, acc2); acc3 = fmaf(W3, v3, acc3);                \
  }

template<int NCH>
__global__ __launch_bounds__(256, 8)
void backproj_kernel(const float* __restrict__ fs,
                     const float4* __restrict__ trig,
                     float* __restrict__ partial) {
    constexpr int ACL = NAANG / NCH;   // even for NCH in {1,2,4,8}
    const int t = threadIdx.x;
    const int lane = t & 63, wave = t >> 6;
    const int lx = lane & 15, lq = lane >> 4;      // 16 x 4 lanes
    const int wx = wave & 1,  wy = wave >> 1;      // 2 x 2 waves
    const int X = blockIdx.x * 32 + wx * 16 + lx;
    const int Y = blockIdx.y * 32 + wy * 16 + lq * 4;  // 4 consecutive y
    const int abase = blockIdx.z * ACL;
    const float xs  = (float)X - 255.5f;
    const float ys0 = (float)Y - 255.5f;
    const float Dg = 850.0f;           // 595/0.7 exactly

    float acc0 = 0.f, acc1 = 0.f, acc2 = 0.f, acc3 = 0.f;
    f32x2 Ag0, Ag1, Ag2, Ag3, Bg0, Bg1, Bg2, Bg3;
    float Af0, Af1, Af2, Af3, Aw0, Aw1, Aw2, Aw3;
    float Bf0, Bf1, Bf2, Bf3, Bw0, Bw1, Bw2, Bw3;

    float4 qc = trig[abase];
    float4 qn = trig[abase + 1];
    GEO(0, qc, Ag0,Ag1,Ag2,Ag3, Af0,Af1,Af2,Af3, Aw0,Aw1,Aw2,Aw3);
    int a = 0;
    for (; a + 2 < ACL; a += 2) {
        float4 q2 = trig[abase + a + 2];
        GEO(a + 1, qn, Bg0,Bg1,Bg2,Bg3, Bf0,Bf1,Bf2,Bf3, Bw0,Bw1,Bw2,Bw3);
        CONSUME(Ag0,Ag1,Ag2,Ag3, Af0,Af1,Af2,Af3, Aw0,Aw1,Aw2,Aw3);
        qn = trig[abase + a + 3];      // max index abase+ACL-1: in range
        GEO(a + 2, q2, Ag0,Ag1,Ag2,Ag3, Af0,Af1,Af2,Af3, Aw0,Aw1,Aw2,Aw3);
        CONSUME(Bg0,Bg1,Bg2,Bg3, Bf0,Bf1,Bf2,Bf3, Bw0,Bw1,Bw2,Bw3);
    }
    GEO(ACL - 1, qn, Bg0,Bg1,Bg2,Bg3, Bf0,Bf1,Bf2,Bf3, Bw0,Bw1,Bw2,Bw3);
    CONSUME(Ag0,Ag1,Ag2,Ag3, Af0,Af1,Af2,Af3, Aw0,Aw1,Aw2,Aw3);
    CONSUME(Bg0,Bg1,Bg2,Bg3, Bf0,Bf1,Bf2,Bf3, Bw0,Bw1,Bw2,Bw3);

    float* outp = partial + ((size_t)blockIdx.z * NPIX + Y) * NPIX + X;
    outp[0 * NPIX] = acc0;
    outp[1 * NPIX] = acc1;
    outp[2 * NPIX] = acc2;
    outp[3 * NPIX] = acc3;
}

// ---------------------------------------------------------------------------
// Kernel 5: sum partials + Dg^2 weight factor + HU window.
// ---------------------------------------------------------------------------
template<int NCH>
__global__ void combine_kernel(const float* __restrict__ partial,
                               float* __restrict__ out) {
    int p = blockIdx.x * 256 + threadIdx.x;
    float s = 0.f;
    #pragma unroll
    for (int c = 0; c < NCH; ++c) s += partial[c * NPIX * NPIX + p];
    // Dg^2 (fan weight, factored out of backproj) * 1000/0.0192/4096
    const float scale = (float)(722500.0 * 1000.0 / 0.0192 / 4096.0);
    out[p] = fmaf(s, scale, 0.005859375f);
}

extern "C" void kernel_launch(void* const* d_in, const int* in_sizes, int n_in,
                              void* d_out, int out_size, void* d_ws, size_t ws_size,
                              hipStream_t stream) {
    const float* x = (const float*)d_in[0];     // (1,1,1152,736) fp32 sinogram
    float* out = (float*)d_out;                 // (1,1,512,512) fp32

    char* ws = (char*)d_ws;
    float*  filt_f = (float*)(ws + OFF_FILTF);
    float*  h      = (float*)(ws + OFF_H);
    float4* trig   = (float4*)(ws + OFF_TRIG);
    float*  fs     = (float*)(ws + OFF_FS);
    float*  part   = (float*)(ws + OFF_PART);

    filt_spec_kernel<<<NHALF, 256, 0, stream>>>(filt_f);
    h_kernel<<<PADN, 256, 0, stream>>>(filt_f, h, trig);
    conv_kernel<<<NAANG / 2, 192, 0, stream>>>(x, h, fs);

    const size_t pbytes = (size_t)NPIX * NPIX * 4;
    if (ws_size >= OFF_PART + 8 * pbytes) {
        backproj_kernel<8><<<dim3(16, 16, 8), 256, 0, stream>>>(fs, trig, part);
        combine_kernel<8><<<NPIX * NPIX / 256, 256, 0, stream>>>(part, out);
    } else if (ws_size >= OFF_PART + 4 * pbytes) {
        backproj_kernel<4><<<dim3(16, 16, 4), 256, 0, stream>>>(fs, trig, part);
        combine_kernel<4><<<NPIX * NPIX / 256, 256, 0, stream>>>(part, out);
    } else if (ws_size >= OFF_PART + 2 * pbytes) {
        backproj_kernel<2><<<dim3(16, 16, 2), 256, 0, stream>>>(fs, trig, part);
        combine_kernel<2><<<NPIX * NPIX / 256, 256, 0, stream>>>(part, out);
    } else {
        backproj_kernel<1><<<dim3(16, 16, 1), 256, 0, stream>>>(fs, trig, part);
        combine_kernel<1><<<NPIX * NPIX / 256, 256, 0, stream>>>(part, out);
    }
}